// Round 9
// baseline (359.121 us; speedup 1.0000x reference)
//
#include <hip/hip_runtime.h>
#include <math.h>

#define NN 100000      // nodes
#define CD 32          // classes / hidden
#define NPB 4          // waves per block in gather kernels
#define G50_NPW 4      // nodes per wave, gather50
#define G32_NPW 4      // nodes per wave, gather32

#define B1N ((NN + 255) >> 8)   // 391 coarse buckets (256 nodes each)
#define EPB_A 2048              // edges per partition block (256 thr x 8)

typedef unsigned int   uint32;
typedef unsigned short ushort16;

// fp32 -> bf16 round-to-nearest-even
__device__ __forceinline__ ushort16 f2b(float f) {
    uint32 u = __float_as_uint(f);
    u = (u + 0x7FFFu + ((u >> 16) & 1u)) >> 16;
    return (ushort16)u;
}
// packed bf16 pair -> two fp32 (exact)
__device__ __forceinline__ float b2f_lo(uint32 u) { return __uint_as_float(u << 16); }
__device__ __forceinline__ float b2f_hi(uint32 u) { return __uint_as_float(u & 0xFFFF0000u); }

// ---------------------------------------------------------------------------
// R22: order-preserving bf16->u16 key space (max-of-keys == key-of-max);
// per-uint gather max = ONE v_pk_max_u16.
__device__ __forceinline__ uint32 pkmax(uint32 a, uint32 b) {
    uint32 d;
    asm("v_pk_max_u16 %0, %1, %2" : "=v"(d) : "v"(a), "v"(b));
    return d;
}
// fp32 -> bf16 key (scalar)
__device__ __forceinline__ uint32 key16(float f) {
    uint32 b = (uint32)f2b(f);
    return b ^ ((__float_as_uint(f) >> 31) ? 0xFFFFu : 0x8000u);
}
// packed key pair -> packed bf16 pair (general sign)
__device__ __forceinline__ uint32 dec_pk(uint32 k) {
    uint32 m = (~k >> 15) & 0x00010001u;            // 1 where original < 0
    uint32 X = 0x80008000u | ((m << 15) - m);       // per half: neg?0xFFFF:0x8000
    return k ^ X;
}

// Inline is64 detection (R17).
__device__ __forceinline__ int edge_is64(const void* edge) {
    const long long* p = (const long long*)edge;
    int lane = threadIdx.x & 63;
    int bad = 0;
    for (int i = lane; i < 512; i += 64) {
        long long v = p[i];
        if (v < 0 || v >= NN) bad = 1;
    }
    unsigned long long anybad = __ballot(bad);
    return (anybad == 0ULL) ? 1 : 0;
}

__device__ __forceinline__ int load_idx(const void* edge, int i, int is64) {
    if (is64) return (int)((const long long*)edge)[i];
    return ((const int*)edge)[i];
}

// ---------------------------------------------------------------------------
// Fused cvt + hist. R24: x is converted to the FEATURE-BLOCKED key layout:
//   xc  = [3][NN][8 uints]  (features 0..47, three contiguous 3.2 MB arrays)
//   xc3 = [NN]              (features 48,49; 400 KB)
// Rationale: the 268 MB workspace re-poison fill sweeps L3 every iteration,
// so the old monolithic 12.8 MB table thrashed the 4 MB per-XCD L2s -> 80 MB
// HBM fetch in gather50. Each pass array is 3.2 MB < 4 MB -> L2-resident.
__global__ __launch_bounds__(256) void cvt_hist_kernel(const float* __restrict__ x,
                                                       uint32* __restrict__ xc,
                                                       uint32* __restrict__ xc3,
                                                       const void* edge, int E,
                                                       int* __restrict__ hist,
                                                       int nblkA) {
    __shared__ int lh[B1N];
    const int t = threadIdx.x;
    if ((int)blockIdx.x < nblkA) {
        const int is64 = edge_is64(edge);
        for (int b = t; b < B1N; b += 256) lh[b] = 0;
        __syncthreads();
        const int e0 = blockIdx.x * EPB_A + t;
#pragma unroll
        for (int k = 0; k < 8; ++k) {
            int e = e0 + k * 256;
            if (e < E) {
                int d = load_idx(edge, E + e, is64);
                atomicAdd(&lh[d >> 8], 1);
            }
        }
        __syncthreads();
        int* gh = hist + (size_t)blockIdx.x * B1N;
        for (int b = t; b < B1N; b += 256) gh[b] = lh[b];
    } else {
        const int tt = (blockIdx.x - nblkA) * 256 + t;
        if (tt < NN * 24) {
            // xc linear index == tt: p*(NN*8) + n*8 + cc
            const int p  = tt / (NN * 8);
            const int r  = tt - p * NN * 8;
            const int n  = r >> 3;
            const int cc = r & 7;
            const int u  = 8 * p + cc;            // uint 0..23 -> features 2u,2u+1
            float2 v = *(const float2*)&x[n * 50 + 2 * u];
            xc[tt] = key16(v.x) | (key16(v.y) << 16);
        } else if (tt < NN * 24 + NN) {
            const int n = tt - NN * 24;
            float2 v = *(const float2*)&x[n * 50 + 48];
            xc3[n] = key16(v.x) | (key16(v.y) << 16);
        }
    }
}

// One block per bin: exclusive scan of hist[b][bin] over blocks b (in place),
// bin total to binTotal[bin]. Supports nblk <= 1024 (4 per thread).
__global__ __launch_bounds__(256) void scanA_kernel(int* __restrict__ hist,
                                                    int nblk,
                                                    int* __restrict__ binTotal) {
    __shared__ int ts[256];
    const int bin = blockIdx.x;
    const int t = threadIdx.x;
    const int base = t * 4;
    int v0 = (base + 0 < nblk) ? hist[(size_t)(base + 0) * B1N + bin] : 0;
    int v1 = (base + 1 < nblk) ? hist[(size_t)(base + 1) * B1N + bin] : 0;
    int v2 = (base + 2 < nblk) ? hist[(size_t)(base + 2) * B1N + bin] : 0;
    int v3 = (base + 3 < nblk) ? hist[(size_t)(base + 3) * B1N + bin] : 0;
    const int s = v0 + v1 + v2 + v3;
    ts[t] = s;
    __syncthreads();
    for (int off = 1; off < 256; off <<= 1) {
        int u = (t >= off) ? ts[t - off] : 0;
        __syncthreads();
        ts[t] += u;
        __syncthreads();
    }
    int e = ts[t] - s;
    if (base + 0 < nblk) { hist[(size_t)(base + 0) * B1N + bin] = e; e += v0; }
    if (base + 1 < nblk) { hist[(size_t)(base + 1) * B1N + bin] = e; e += v1; }
    if (base + 2 < nblk) { hist[(size_t)(base + 2) * B1N + bin] = e; e += v2; }
    if (base + 3 < nblk) { hist[(size_t)(base + 3) * B1N + bin] = e; e += v3; }
    if (t == 255) binTotal[bin] = ts[255];
}

// In-block exclusive scan of binTotal[B1N] -> lbase[B1N+1] (LDS).
__device__ __forceinline__ void scan_bins_lds(const int* __restrict__ binTotal,
                                              int* ts, int* lbase) {
    const int t = threadIdx.x;
    const int base = t * 2;
    const int v0 = (base + 0 < B1N) ? binTotal[base + 0] : 0;
    const int v1 = (base + 1 < B1N) ? binTotal[base + 1] : 0;
    const int s = v0 + v1;
    ts[t] = s;
    __syncthreads();
    for (int off = 1; off < 256; off <<= 1) {
        int u = (t >= off) ? ts[t - off] : 0;
        __syncthreads();
        ts[t] += u;
        __syncthreads();
    }
    const int e = ts[t] - s;
    if (base + 0 < B1N) lbase[base + 0] = e;
    if (base + 1 < B1N) lbase[base + 1] = e + v0;
    if (t == 255) lbase[B1N] = ts[255];     // == E
    __syncthreads();
}

__global__ __launch_bounds__(256) void scatter_kernel(const void* edge, int E,
                                                      const int* __restrict__ hist,
                                                      const int* __restrict__ binTotal,
                                                      uint32* __restrict__ bucketed) {
    __shared__ int ts[256];
    __shared__ int lbase[B1N + 1];
    __shared__ int cur[B1N];
    const int is64 = edge_is64(edge);
    const int t = threadIdx.x;
    scan_bins_lds(binTotal, ts, lbase);
    const int* gh = hist + (size_t)blockIdx.x * B1N;
    for (int b = t; b < B1N; b += 256) cur[b] = lbase[b] + gh[b];
    __syncthreads();
    const int e0 = blockIdx.x * EPB_A + t;
#pragma unroll
    for (int k = 0; k < 8; ++k) {
        int e = e0 + k * 256;
        if (e < E) {
            int s = load_idx(edge, e, is64);
            int d = load_idx(edge, E + e, is64);
            int pos = atomicAdd(&cur[d >> 8], 1);   // LDS atomic
            bucketed[pos] = (uint32)s | ((uint32)(d & 255) << 17);
        }
    }
}

__global__ __launch_bounds__(256) void bucket_kernel(const uint32* __restrict__ bucketed,
                                                     const int* __restrict__ binTotal,
                                                     int* __restrict__ offsets,
                                                     int* __restrict__ csr_src) {
    __shared__ int ts[256];
    __shared__ int lbase[B1N + 1];
    __shared__ int h[256];
    __shared__ int sc[256];
    __shared__ int cur[256];
    const int bkt = blockIdx.x;
    const int t = threadIdx.x;
    scan_bins_lds(binTotal, ts, lbase);
    const int start = lbase[bkt];
    const int end   = lbase[bkt + 1];
    h[t] = 0;
    __syncthreads();
    for (int i = start + t; i < end; i += 256)
        atomicAdd(&h[bucketed[i] >> 17], 1);        // LDS atomic
    __syncthreads();
    const int v = h[t];
    sc[t] = v;
    __syncthreads();
    for (int off = 1; off < 256; off <<= 1) {
        int u = (t >= off) ? sc[t - off] : 0;
        __syncthreads();
        sc[t] += u;
        __syncthreads();
    }
    const int excl = sc[t] - v;
    const int node = bkt * 256 + t;
    if (node < NN) offsets[node] = start + excl;    // coalesced
    cur[t] = start + excl;
    __syncthreads();
    for (int i = start + t; i < end; i += 256) {
        uint32 p = bucketed[i];
        int pos = atomicAdd(&cur[p >> 17], 1);      // LDS atomic
        csr_src[pos] = (int)(p & 0x1FFFFu);         // L2-local scatter (16KB window)
    }
    if (bkt == B1N - 1 && t == 0) offsets[NN] = end;   // == E
}

// ---------------------------------------------------------------------------
// gather50 (R24): 3 feature-block passes in ONE dispatch (pass = blockIdx
// partition -> time-phased, each pass's 3.2 MB table is L2-resident).
// Lane mapping: e = lane&7 (edge slot), c = lane>>3 (chunk). Window index
// load csr_src[ib+lane] is already sub-group aligned for stride-8 slots
// (source lane k has k&7==e -> shfl stays in-sub-group, divergence-safe).
// Pass 0 also folds in the uint-24 column (each lane's OWN edge, no shfl).
// 4 nodes per wave, index loads issued up front (R23 latency pipelining).

__global__ void gather50_kernel(const uint32* __restrict__ xc,
                                const uint32* __restrict__ xc3,
                                const int* __restrict__ offsets,
                                const int* __restrict__ csr_src,
                                uint32* __restrict__ aggp,
                                uint32* __restrict__ agg24,
                                int gb) {
    const int tid  = threadIdx.x;
    const int g    = tid >> 6;
    const int lane = tid & 63;
    const int e    = lane & 7;
    const int c    = lane >> 3;
    const int pass = blockIdx.x / gb;
    const int blk  = blockIdx.x - pass * gb;
    const int n0   = (blk * NPB + g) * G50_NPW;
    if (n0 >= NN) return;
    const bool p0 = (pass == 0);

    const char* tb = (const char*)(xc + (size_t)pass * NN * 8);
    const uint32 coff = (uint32)(c << 2);

    int beg[G50_NPW], end[G50_NPW], mm[G50_NPW], sidx[G50_NPW];
#pragma unroll
    for (int q = 0; q < G50_NPW; ++q) {
        const int n = n0 + q;
        const bool ok = (n < NN);
        beg[q] = ok ? offsets[n] : 0;
        end[q] = ok ? offsets[n + 1] : 0;
        int d = end[q] - beg[q];
        mm[q] = d < 64 ? d : 64;
    }
#pragma unroll
    for (int q = 0; q < G50_NPW; ++q)
        sidx[q] = (lane < mm[q]) ? csr_src[beg[q] + lane] : 0;   // coalesced

    uint32 acc[G50_NPW], a24[G50_NPW];
#pragma unroll
    for (int q = 0; q < G50_NPW; ++q) { acc[q] = 0; a24[q] = 0; }

#pragma unroll
    for (int q = 0; q < G50_NPW; ++q) {
        for (int k = e; k < mm[q]; k += 8) {
            int s = __shfl(sidx[q], k);      // in-sub-group source
            acc[q] = pkmax(acc[q], *(const uint32*)(tb + ((((uint32)s) << 5) | coff)));
        }
        if (p0 && lane < mm[q]) a24[q] = pkmax(a24[q], xc3[sidx[q]]);
    }
    // Rare extra windows (degree > 64)
#pragma unroll
    for (int q = 0; q < G50_NPW; ++q) {
        for (int ib = beg[q] + 64; ib < end[q]; ib += 64) {
            const int rem = end[q] - ib;
            const int m = rem < 64 ? rem : 64;
            int sx = (lane < m) ? csr_src[ib + lane] : 0;
            for (int k = e; k < m; k += 8) {
                int s = __shfl(sx, k);
                acc[q] = pkmax(acc[q], *(const uint32*)(tb + ((((uint32)s) << 5) | coff)));
            }
            if (p0 && lane < m) a24[q] = pkmax(a24[q], xc3[sx]);
        }
    }

#pragma unroll
    for (int q = 0; q < G50_NPW; ++q) {
        const int n = n0 + q;
        uint32 r = acc[q];
        r = pkmax(r, (uint32)__shfl_xor((int)r, 1));   // reduce across e (low bits)
        r = pkmax(r, (uint32)__shfl_xor((int)r, 2));
        r = pkmax(r, (uint32)__shfl_xor((int)r, 4));
        if (e == 0 && n < NN) {
            aggp[((size_t)pass * NN + n) * 8 + c] =
                (beg[q] == end[q]) ? 0x80008000u : r;
        }
        if (p0) {
            uint32 s24 = a24[q];
            s24 = pkmax(s24, (uint32)__shfl_xor((int)s24, 1));
            s24 = pkmax(s24, (uint32)__shfl_xor((int)s24, 2));
            s24 = pkmax(s24, (uint32)__shfl_xor((int)s24, 4));
            s24 = pkmax(s24, (uint32)__shfl_xor((int)s24, 8));
            s24 = pkmax(s24, (uint32)__shfl_xor((int)s24, 16));
            s24 = pkmax(s24, (uint32)__shfl_xor((int)s24, 32));
            if (lane == 0 && n < NN)
                agg24[n] = (beg[q] == end[q]) ? 0x80008000u : s24;
        }
    }
}

// ---------------------------------------------------------------------------
// gather32 (R21/R23 structure, R24: 4 nodes per wave).
__device__ __forceinline__ void g32_window(uint32* a_, int sidx, int mm,
                                           const char* hbase, uint32 coff,
                                           int e, int lb) {
    int k = e;
    for (; k + 12 < mm; k += 16) {
        const int m = lb + (k >> 2);
        int s0 = __shfl(sidx, m);              // intra-quarter sources
        int s1 = __shfl(sidx, m + 1);
        int s2 = __shfl(sidx, m + 2);
        int s3 = __shfl(sidx, m + 3);
        uint32 u0 = *(const uint32*)(hbase + ((((uint32)s0) << 6) | coff));
        uint32 u1 = *(const uint32*)(hbase + ((((uint32)s1) << 6) | coff));
        uint32 u2 = *(const uint32*)(hbase + ((((uint32)s2) << 6) | coff));
        uint32 u3 = *(const uint32*)(hbase + ((((uint32)s3) << 6) | coff));
        a_[0] = pkmax(a_[0], u0); a_[1] = pkmax(a_[1], u1);
        a_[2] = pkmax(a_[2], u2); a_[3] = pkmax(a_[3], u3);
    }
    for (; k < mm; k += 4) {
        int s = __shfl(sidx, lb + (k >> 2));
        uint32 u = *(const uint32*)(hbase + ((((uint32)s) << 6) | coff));
        a_[0] = pkmax(a_[0], u);
    }
}

__global__ void gather32_kernel(const uint32* __restrict__ hb,
                                const int* __restrict__ offsets,
                                const int* __restrict__ csr_src,
                                uint32* __restrict__ aggB) {
    const int tid  = threadIdx.x;
    const int g    = tid >> 6;
    const int lane = tid & 63;
    const int e    = lane >> 4;        // quarter-wave: edge slot mod 4
    const int c    = lane & 15;        // uint chunk
    const int n0   = (blockIdx.x * NPB + g) * G32_NPW;
    if (n0 >= NN) return;

    const char* hbase = (const char*)hb;
    const uint32 coff = (uint32)(c << 2);
    const int lb = e << 4;             // this quarter's lane base
    const int myidx = 4 * c + e;       // R21 permuted window layout

    int beg[G32_NPW], end[G32_NPW], mm[G32_NPW], sidx[G32_NPW];
#pragma unroll
    for (int q = 0; q < G32_NPW; ++q) {
        const int n = n0 + q;
        const bool ok = (n < NN);
        beg[q] = ok ? offsets[n] : 0;
        end[q] = ok ? offsets[n + 1] : 0;
        int d = end[q] - beg[q];
        mm[q] = d < 64 ? d : 64;
    }
#pragma unroll
    for (int q = 0; q < G32_NPW; ++q)
        sidx[q] = (myidx < mm[q]) ? csr_src[beg[q] + myidx] : 0;

    uint32 A[G32_NPW][4];
#pragma unroll
    for (int q = 0; q < G32_NPW; ++q)
#pragma unroll
        for (int k = 0; k < 4; ++k) A[q][k] = 0;

#pragma unroll
    for (int q = 0; q < G32_NPW; ++q)
        g32_window(A[q], sidx[q], mm[q], hbase, coff, e, lb);
    // Rare extra windows (degree > 64)
#pragma unroll
    for (int q = 0; q < G32_NPW; ++q) {
        for (int ib = beg[q] + 64; ib < end[q]; ib += 64) {
            const int rem = end[q] - ib;
            const int m = rem < 64 ? rem : 64;
            int sx = (myidx < m) ? csr_src[ib + myidx] : 0;
            g32_window(A[q], sx, m, hbase, coff, e, lb);
        }
    }

#pragma unroll
    for (int q = 0; q < G32_NPW; ++q) {
        const int n = n0 + q;
        uint32 r = pkmax(pkmax(A[q][0], A[q][1]), pkmax(A[q][2], A[q][3]));
        r = pkmax(r, (uint32)__shfl_xor((int)r, 16));   // combine edge slots
        r = pkmax(r, (uint32)__shfl_xor((int)r, 32));
        if (lane < 16 && n < NN)
            aggB[(size_t)n * 16 + lane] = (beg[q] == end[q]) ? 0x80008000u : r;
    }
}

// ---------------------------------------------------------------------------
// dense50 (R24): lane-per-node, split-layout inputs (aggp/agg24, xc/xc3).
// Wave-uniform weight addresses scalarize to s_load (R11-proven property).
__global__ void dense50_kernel(const uint32* __restrict__ aggp,
                               const uint32* __restrict__ agg24,
                               const uint32* __restrict__ xc,
                               const uint32* __restrict__ xc3,
                               const float* __restrict__ Wl,
                               const float* __restrict__ bl,
                               const float* __restrict__ Wr,
                               uint32* __restrict__ out) {
    const int n = blockIdx.x * blockDim.x + threadIdx.x;
    if (n >= NN) return;

    float acc[CD];
#pragma unroll
    for (int j = 0; j < CD; ++j) acc[j] = bl[j];

#pragma unroll
    for (int side = 0; side < 2; ++side) {
        const uint32* tp = side ? xc  : aggp;
        const uint32* t3 = side ? xc3 : agg24;
        const float*  W  = side ? Wr  : Wl;
#pragma unroll
        for (int p = 0; p < 3; ++p) {
            const uint32* row = tp + ((size_t)p * NN + n) * 8;
#pragma unroll
            for (int q = 0; q < 4; ++q) {
                uint2 uu = *(const uint2*)&row[q * 2];
                uint32 ux = dec_pk(uu.x), uy = dec_pk(uu.y);
                float d0 = b2f_lo(ux), d1 = b2f_hi(ux);
                float d2 = b2f_lo(uy), d3 = b2f_hi(uy);
                const float* w = W + (p * 16 + q * 4) * CD;
#pragma unroll
                for (int j = 0; j < CD; ++j)
                    acc[j] += d0 * w[j] + d1 * w[CD + j] + d2 * w[2 * CD + j] + d3 * w[3 * CD + j];
            }
        }
        {
            uint32 u = dec_pk(t3[n]);
            float d0 = b2f_lo(u), d1 = b2f_hi(u);
            const float* w = W + 48 * CD;
#pragma unroll
            for (int j = 0; j < CD; ++j)
                acc[j] += d0 * w[j] + d1 * w[CD + j];
        }
    }

    uint32* orow = out + (size_t)n * 16;
#pragma unroll
    for (int c = 0; c < CD / 2; ++c) {
        float a0 = fmaxf(acc[2 * c],     0.0f);
        float a1 = fmaxf(acc[2 * c + 1], 0.0f);
        orow[c] = ((uint32)f2b(a0) | ((uint32)f2b(a1) << 16)) | 0x80008000u;
    }
}

// ---------------------------------------------------------------------------
// Dense kernel for layers 2/3 (unchanged, R11-proven). Key-encoded inputs;
// MODE 0 = relu -> keys; MODE 2 = log_softmax -> fp32.
template <int DIN, int ASTR, int HSTR, int OSTR, int MODE>
__global__ void dense_kernel(const uint32* __restrict__ aggB,
                             const uint32* __restrict__ hB,
                             const float* __restrict__ Wl,
                             const float* __restrict__ bl,
                             const float* __restrict__ Wr,
                             void* __restrict__ out_v) {
    const int n = blockIdx.x * blockDim.x + threadIdx.x;
    if (n >= NN) return;

    float acc[CD];
#pragma unroll
    for (int j = 0; j < CD; ++j) acc[j] = bl[j];

    {
        const uint32* row = aggB + (size_t)n * ASTR;
        for (int c = 0; c < DIN / 4; ++c) {
            uint2 u = *(const uint2*)&row[c * 2];
            u.x = dec_pk(u.x); u.y = dec_pk(u.y);
            float d0 = b2f_lo(u.x), d1 = b2f_hi(u.x);
            float d2 = b2f_lo(u.y), d3 = b2f_hi(u.y);
            const float* w = Wl + c * 4 * CD;
#pragma unroll
            for (int j = 0; j < CD; ++j)
                acc[j] += d0 * w[j] + d1 * w[CD + j] + d2 * w[2 * CD + j] + d3 * w[3 * CD + j];
        }
    }
    {
        const uint32* row = hB + (size_t)n * HSTR;
        for (int c = 0; c < DIN / 4; ++c) {
            uint2 u = *(const uint2*)&row[c * 2];
            u.x = dec_pk(u.x); u.y = dec_pk(u.y);
            float d0 = b2f_lo(u.x), d1 = b2f_hi(u.x);
            float d2 = b2f_lo(u.y), d3 = b2f_hi(u.y);
            const float* w = Wr + c * 4 * CD;
#pragma unroll
            for (int j = 0; j < CD; ++j)
                acc[j] += d0 * w[j] + d1 * w[CD + j] + d2 * w[2 * CD + j] + d3 * w[3 * CD + j];
        }
    }

    if (MODE == 0) {
        uint32* orow = (uint32*)out_v + (size_t)n * OSTR;
#pragma unroll
        for (int c = 0; c < CD / 2; ++c) {
            float a0 = fmaxf(acc[2 * c],     0.0f);
            float a1 = fmaxf(acc[2 * c + 1], 0.0f);
            orow[c] = ((uint32)f2b(a0) | ((uint32)f2b(a1) << 16)) | 0x80008000u;
        }
    } else {
        float m = acc[0];
#pragma unroll
        for (int j = 1; j < CD; ++j) m = fmaxf(m, acc[j]);
        float s = 0.0f;
#pragma unroll
        for (int j = 0; j < CD; ++j) s += expf(acc[j] - m);
        const float lse = m + logf(s);
        float* orow = (float*)out_v + (size_t)n * CD;
#pragma unroll
        for (int j = 0; j < CD; ++j) orow[j] = acc[j] - lse;
    }
}

// ---------------------------------------------------------------------------
extern "C" void kernel_launch(void* const* d_in, const int* in_sizes, int n_in,
                              void* d_out, int out_size, void* d_ws, size_t ws_size,
                              hipStream_t stream) {
    const float* x    = (const float*)d_in[0];
    const void*  edge = d_in[1];
    const float* Wl1 = (const float*)d_in[2];
    const float* bl1 = (const float*)d_in[3];
    const float* Wr1 = (const float*)d_in[4];
    const float* Wl2 = (const float*)d_in[5];
    const float* bl2 = (const float*)d_in[6];
    const float* Wr2 = (const float*)d_in[7];
    const float* Wl3 = (const float*)d_in[8];
    const float* bl3 = (const float*)d_in[9];
    const float* Wr3 = (const float*)d_in[10];

    const int E = in_sizes[1] / 2;

    // Workspace carve-up (256B aligned). bucketed+hist live in d_out (dead
    // before aggp/agg24 are written there); h2b reuses xc (dead after
    // dense50); agg3 reuses h1b (dead after dense-L2).
    char* ws = (char*)d_ws;
    size_t off = 0;
    auto carve = [&](size_t bytes) {
        void* p = ws + off;
        off = (off + bytes + 255) & ~(size_t)255;
        return p;
    };
    int*    offsets   = (int*)   carve((size_t)(NN + 1) * 4);
    int*    binTotal  = (int*)   carve((size_t)B1N * 4);
    int*    csr_src   = (int*)   carve((size_t)E * 4);
    uint32* xc        = (uint32*)carve((size_t)NN * 24 * 4);  // 9.6 MB (3 passes)
    uint32* xc3       = (uint32*)carve((size_t)NN * 4);       // 0.4 MB
    uint32* h1b       = (uint32*)carve((size_t)NN * 16 * 4);  // 6.4 MB
    (void)ws_size; (void)n_in; (void)out_size;

    uint32* bucketed = (uint32*)d_out;     // 6.4 MB, dead before aggp
    int*    hist     = (int*)((char*)d_out + (((size_t)E * 4 + 255) & ~(size_t)255));
    uint32* aggp  = (uint32*)d_out;                              // 9.6 MB
    uint32* agg24 = (uint32*)d_out + (size_t)NN * 24;            // 0.4 MB
    uint32* agg2 = (uint32*)d_out;         // L2 agg, stride 16 (aggp dead)
    uint32* h2b  = xc;                     // xc dead after dense50
    uint32* agg3 = h1b;                    // h1b dead after dense-L2

    // CSR build, LDS-atomic bucketing; cvt fused into the hist dispatch.
    const int nblkA = (E + EPB_A - 1) / EPB_A;     // 782 for E=1.6M
    const int cvtb  = (NN * 25 + 255) / 256;       // 9766
    cvt_hist_kernel<<<nblkA + cvtb, 256, 0, stream>>>(x, xc, xc3, edge, E, hist, nblkA);
    scanA_kernel<<<B1N, 256, 0, stream>>>(hist, nblkA, binTotal);
    scatter_kernel<<<nblkA, 256, 0, stream>>>(edge, E, hist, binTotal, bucketed);
    bucket_kernel<<<B1N, 256, 0, stream>>>(bucketed, binTotal, offsets, csr_src);

    const int gb50 = (NN + NPB * G50_NPW - 1) / (NPB * G50_NPW);  // 6250
    const int gb32 = (NN + NPB * G32_NPW - 1) / (NPB * G32_NPW);  // 6250
    const int db   = (NN + 255) / 256;                            // lane per node

    // Layer 1: 50 -> 32, relu (3 feature-block passes, one dispatch)
    gather50_kernel<<<3 * gb50, 256, 0, stream>>>(xc, xc3, offsets, csr_src,
                                                  aggp, agg24, gb50);
    dense50_kernel<<<db, 256, 0, stream>>>(aggp, agg24, xc, xc3, Wl1, bl1, Wr1, h1b);
    // Layer 2: 32 -> 32, relu
    gather32_kernel<<<gb32, 256, 0, stream>>>(h1b, offsets, csr_src, agg2);
    dense_kernel<32, 16, 16, 16, 0><<<db, 256, 0, stream>>>(agg2, h1b, Wl2, bl2, Wr2, h2b);
    // Layer 3: 32 -> 32, log_softmax -> fp32 d_out
    gather32_kernel<<<gb32, 256, 0, stream>>>(h2b, offsets, csr_src, agg3);
    dense_kernel<32, 16, 16, 0, 2><<<db, 256, 0, stream>>>(agg3, h2b, Wl3, bl3, Wr3, d_out);
}

// Round 10
// 293.981 us; speedup vs baseline: 1.2216x; 1.2216x over previous
//
#include <hip/hip_runtime.h>
#include <math.h>

#define NN 100000      // nodes
#define CD 32          // classes / hidden
#define NPB 4          // waves per block in gather kernels
#define G_NPW 4        // nodes per wave (R25: 2 -> 4, amortize idx latency)

#define B1N ((NN + 255) >> 8)   // 391 coarse buckets (256 nodes each)
#define EPB_A 2048              // edges per partition block (256 thr x 8)

typedef unsigned int   uint32;
typedef unsigned short ushort16;

// fp32 -> bf16 round-to-nearest-even
__device__ __forceinline__ ushort16 f2b(float f) {
    uint32 u = __float_as_uint(f);
    u = (u + 0x7FFFu + ((u >> 16) & 1u)) >> 16;
    return (ushort16)u;
}
// packed bf16 pair -> two fp32 (exact)
__device__ __forceinline__ float b2f_lo(uint32 u) { return __uint_as_float(u << 16); }
__device__ __forceinline__ float b2f_hi(uint32 u) { return __uint_as_float(u & 0xFFFF0000u); }

// ---------------------------------------------------------------------------
// R22: order-preserving bf16->u16 key space (max-of-keys == key-of-max);
// per-uint gather max = ONE v_pk_max_u16.
__device__ __forceinline__ uint32 pkmax(uint32 a, uint32 b) {
    uint32 d;
    asm("v_pk_max_u16 %0, %1, %2" : "=v"(d) : "v"(a), "v"(b));
    return d;
}
// fp32 -> bf16 key (scalar)
__device__ __forceinline__ uint32 key16(float f) {
    uint32 b = (uint32)f2b(f);
    return b ^ ((__float_as_uint(f) >> 31) ? 0xFFFFu : 0x8000u);
}
// packed key pair -> packed bf16 pair (general sign)
__device__ __forceinline__ uint32 dec_pk(uint32 k) {
    uint32 m = (~k >> 15) & 0x00010001u;            // 1 where original < 0
    uint32 X = 0x80008000u | ((m << 15) - m);       // per half: neg?0xFFFF:0x8000
    return k ^ X;
}

// Inline is64 detection (R17).
__device__ __forceinline__ int edge_is64(const void* edge) {
    const long long* p = (const long long*)edge;
    int lane = threadIdx.x & 63;
    int bad = 0;
    for (int i = lane; i < 512; i += 64) {
        long long v = p[i];
        if (v < 0 || v >= NN) bad = 1;
    }
    unsigned long long anybad = __ballot(bad);
    return (anybad == 0ULL) ? 1 : 0;
}

__device__ __forceinline__ int load_idx(const void* edge, int i, int is64) {
    if (is64) return (int)((const long long*)edge)[i];
    return ((const int*)edge)[i];
}

// ---------------------------------------------------------------------------
// Fused cvt + hist (R22). R25: REVERTED to the monolithic stride-32 xb —
// R24's feature-blocked 3-pass layout tripled per-node latency rounds
// (gather50 28->68 us) and un-coalesced dense50. Lesson: gather cost is
// latency-rounds/node, not table footprint.
__global__ __launch_bounds__(256) void cvt_hist_kernel(const float* __restrict__ x,
                                                       uint32* __restrict__ xb,
                                                       const void* edge, int E,
                                                       int* __restrict__ hist,
                                                       int nblkA) {
    __shared__ int lh[B1N];
    const int t = threadIdx.x;
    if ((int)blockIdx.x < nblkA) {
        const int is64 = edge_is64(edge);
        for (int b = t; b < B1N; b += 256) lh[b] = 0;
        __syncthreads();
        const int e0 = blockIdx.x * EPB_A + t;
#pragma unroll
        for (int k = 0; k < 8; ++k) {
            int e = e0 + k * 256;
            if (e < E) {
                int d = load_idx(edge, E + e, is64);
                atomicAdd(&lh[d >> 8], 1);
            }
        }
        __syncthreads();
        int* gh = hist + (size_t)blockIdx.x * B1N;
        for (int b = t; b < B1N; b += 256) gh[b] = lh[b];
    } else {
        const int tt = (blockIdx.x - nblkA) * 256 + t;
        if (tt >= NN * 32) return;
        const int n = tt >> 5;
        const int c = tt & 31;
        if (c >= 25) { xb[tt] = 0; return; }
        float2 v = *(const float2*)&x[n * 50 + 2 * c];
        xb[tt] = key16(v.x) | (key16(v.y) << 16);
    }
}

// One block per bin: exclusive scan of hist[b][bin] over blocks b (in place),
// bin total to binTotal[bin]. Supports nblk <= 1024 (4 per thread).
__global__ __launch_bounds__(256) void scanA_kernel(int* __restrict__ hist,
                                                    int nblk,
                                                    int* __restrict__ binTotal) {
    __shared__ int ts[256];
    const int bin = blockIdx.x;
    const int t = threadIdx.x;
    const int base = t * 4;
    int v0 = (base + 0 < nblk) ? hist[(size_t)(base + 0) * B1N + bin] : 0;
    int v1 = (base + 1 < nblk) ? hist[(size_t)(base + 1) * B1N + bin] : 0;
    int v2 = (base + 2 < nblk) ? hist[(size_t)(base + 2) * B1N + bin] : 0;
    int v3 = (base + 3 < nblk) ? hist[(size_t)(base + 3) * B1N + bin] : 0;
    const int s = v0 + v1 + v2 + v3;
    ts[t] = s;
    __syncthreads();
    for (int off = 1; off < 256; off <<= 1) {
        int u = (t >= off) ? ts[t - off] : 0;
        __syncthreads();
        ts[t] += u;
        __syncthreads();
    }
    int e = ts[t] - s;
    if (base + 0 < nblk) { hist[(size_t)(base + 0) * B1N + bin] = e; e += v0; }
    if (base + 1 < nblk) { hist[(size_t)(base + 1) * B1N + bin] = e; e += v1; }
    if (base + 2 < nblk) { hist[(size_t)(base + 2) * B1N + bin] = e; e += v2; }
    if (base + 3 < nblk) { hist[(size_t)(base + 3) * B1N + bin] = e; e += v3; }
    if (t == 255) binTotal[bin] = ts[255];
}

// In-block exclusive scan of binTotal[B1N] -> lbase[B1N+1] (LDS).
__device__ __forceinline__ void scan_bins_lds(const int* __restrict__ binTotal,
                                              int* ts, int* lbase) {
    const int t = threadIdx.x;
    const int base = t * 2;
    const int v0 = (base + 0 < B1N) ? binTotal[base + 0] : 0;
    const int v1 = (base + 1 < B1N) ? binTotal[base + 1] : 0;
    const int s = v0 + v1;
    ts[t] = s;
    __syncthreads();
    for (int off = 1; off < 256; off <<= 1) {
        int u = (t >= off) ? ts[t - off] : 0;
        __syncthreads();
        ts[t] += u;
        __syncthreads();
    }
    const int e = ts[t] - s;
    if (base + 0 < B1N) lbase[base + 0] = e;
    if (base + 1 < B1N) lbase[base + 1] = e + v0;
    if (t == 255) lbase[B1N] = ts[255];     // == E
    __syncthreads();
}

__global__ __launch_bounds__(256) void scatter_kernel(const void* edge, int E,
                                                      const int* __restrict__ hist,
                                                      const int* __restrict__ binTotal,
                                                      uint32* __restrict__ bucketed) {
    __shared__ int ts[256];
    __shared__ int lbase[B1N + 1];
    __shared__ int cur[B1N];
    const int is64 = edge_is64(edge);
    const int t = threadIdx.x;
    scan_bins_lds(binTotal, ts, lbase);
    const int* gh = hist + (size_t)blockIdx.x * B1N;
    for (int b = t; b < B1N; b += 256) cur[b] = lbase[b] + gh[b];
    __syncthreads();
    const int e0 = blockIdx.x * EPB_A + t;
#pragma unroll
    for (int k = 0; k < 8; ++k) {
        int e = e0 + k * 256;
        if (e < E) {
            int s = load_idx(edge, e, is64);
            int d = load_idx(edge, E + e, is64);
            int pos = atomicAdd(&cur[d >> 8], 1);   // LDS atomic
            bucketed[pos] = (uint32)s | ((uint32)(d & 255) << 17);
        }
    }
}

__global__ __launch_bounds__(256) void bucket_kernel(const uint32* __restrict__ bucketed,
                                                     const int* __restrict__ binTotal,
                                                     int* __restrict__ offsets,
                                                     int* __restrict__ csr_src) {
    __shared__ int ts[256];
    __shared__ int lbase[B1N + 1];
    __shared__ int h[256];
    __shared__ int sc[256];
    __shared__ int cur[256];
    const int bkt = blockIdx.x;
    const int t = threadIdx.x;
    scan_bins_lds(binTotal, ts, lbase);
    const int start = lbase[bkt];
    const int end   = lbase[bkt + 1];
    h[t] = 0;
    __syncthreads();
    for (int i = start + t; i < end; i += 256)
        atomicAdd(&h[bucketed[i] >> 17], 1);        // LDS atomic
    __syncthreads();
    const int v = h[t];
    sc[t] = v;
    __syncthreads();
    for (int off = 1; off < 256; off <<= 1) {
        int u = (t >= off) ? sc[t - off] : 0;
        __syncthreads();
        sc[t] += u;
        __syncthreads();
    }
    const int excl = sc[t] - v;
    const int node = bkt * 256 + t;
    if (node < NN) offsets[node] = start + excl;    // coalesced
    cur[t] = start + excl;
    __syncthreads();
    for (int i = start + t; i < end; i += 256) {
        uint32 p = bucketed[i];
        int pos = atomicAdd(&cur[p >> 17], 1);      // LDS atomic
        csr_src[pos] = (int)(p & 0x1FFFFu);         // L2-local scatter (16KB window)
    }
    if (bkt == B1N - 1 && t == 0) offsets[NN] = end;   // == E
}

// ---------------------------------------------------------------------------
// Gather-max kernels, key space. R23 structure (permuted coalesced window
// load + in-sub-group shfl), R25: FOUR nodes per wave — all 4 index-window
// loads issue back-to-back before any row round, so per-node amortized
// latency approaches 1 round and 4x row loads are in flight per wave.

__device__ __forceinline__ void g50_window(uint32* a_, int sidx, int mm,
                                           const char* hbase, uint32 joff,
                                           int p, int lb) {
    int k = p;
    for (; k + 14 < mm; k += 16) {
        const int kh = lb + (k >> 1);
#pragma unroll
        for (int kk = 0; kk < 8; ++kk) {
            int s = __shfl(sidx, kh + kk);     // intra-half source (R21 layout)
            uint32 u = *(const uint32*)(hbase + ((((uint32)s) << 7) | joff));
            a_[kk] = pkmax(a_[kk], u);
        }
    }
    for (; k + 6 < mm; k += 8) {
        const int kh = lb + (k >> 1);
#pragma unroll
        for (int kk = 0; kk < 4; ++kk) {
            int s = __shfl(sidx, kh + kk);
            uint32 u = *(const uint32*)(hbase + ((((uint32)s) << 7) | joff));
            a_[kk] = pkmax(a_[kk], u);
        }
    }
    for (; k < mm; k += 2) {
        int s = __shfl(sidx, lb + (k >> 1));
        uint32 u = *(const uint32*)(hbase + ((((uint32)s) << 7) | joff));
        a_[0] = pkmax(a_[0], u);
    }
}

__global__ void gather50_kernel(const uint32* __restrict__ hb,
                                const int* __restrict__ offsets,
                                const int* __restrict__ csr_src,
                                uint32* __restrict__ aggB) {
    const int tid  = threadIdx.x;
    const int g    = tid >> 6;
    const int lane = tid & 63;
    const int p    = lane >> 5;        // half-wave: edge parity
    const int j    = lane & 31;        // uint chunk
    const int n0   = (blockIdx.x * NPB + g) * G_NPW;
    if (n0 >= NN) return;

    const char* hbase = (const char*)hb;
    const uint32 joff = (uint32)(j << 2);
    const int lb = p << 5;             // this half's lane base
    const int myidx = 2 * j + p;       // R21 permuted window layout

    int beg[G_NPW], end[G_NPW], mm[G_NPW], sidx[G_NPW];
#pragma unroll
    for (int q = 0; q < G_NPW; ++q) {
        const int n = n0 + q;
        const bool ok = (n < NN);
        beg[q] = ok ? offsets[n] : 0;
        end[q] = ok ? offsets[n + 1] : 0;
        int d = end[q] - beg[q];
        mm[q] = d < 64 ? d : 64;
    }
#pragma unroll
    for (int q = 0; q < G_NPW; ++q)
        sidx[q] = (myidx < mm[q]) ? csr_src[beg[q] + myidx] : 0;   // coalesced

    uint32 A[G_NPW][8];
#pragma unroll
    for (int q = 0; q < G_NPW; ++q)
#pragma unroll
        for (int k = 0; k < 8; ++k) A[q][k] = 0;

#pragma unroll
    for (int q = 0; q < G_NPW; ++q)
        g50_window(A[q], sidx[q], mm[q], hbase, joff, p, lb);
    // Rare extra windows (degree > 64)
#pragma unroll
    for (int q = 0; q < G_NPW; ++q) {
        for (int ib = beg[q] + 64; ib < end[q]; ib += 64) {
            const int rem = end[q] - ib;
            const int m = rem < 64 ? rem : 64;
            int sx = (myidx < m) ? csr_src[ib + myidx] : 0;
            g50_window(A[q], sx, m, hbase, joff, p, lb);
        }
    }

#pragma unroll
    for (int q = 0; q < G_NPW; ++q) {
        const int n = n0 + q;
#pragma unroll
        for (int off2 = 4; off2 > 0; off2 >>= 1)
#pragma unroll
            for (int k = 0; k < off2; ++k)
                A[q][k] = pkmax(A[q][k], A[q][k + off2]);
        uint32 r = A[q][0];
        r = pkmax(r, (uint32)__shfl_xor((int)r, 32));   // combine parity halves
        if (p == 0 && j < 25 && n < NN)
            aggB[(size_t)n * 32 + j] = (beg[q] == end[q]) ? 0x80008000u : r;
    }
}

__device__ __forceinline__ void g32_window(uint32* a_, int sidx, int mm,
                                           const char* hbase, uint32 coff,
                                           int e, int lb) {
    int k = e;
    for (; k + 12 < mm; k += 16) {
        const int m = lb + (k >> 2);
        int s0 = __shfl(sidx, m);              // intra-quarter sources
        int s1 = __shfl(sidx, m + 1);
        int s2 = __shfl(sidx, m + 2);
        int s3 = __shfl(sidx, m + 3);
        uint32 u0 = *(const uint32*)(hbase + ((((uint32)s0) << 6) | coff));
        uint32 u1 = *(const uint32*)(hbase + ((((uint32)s1) << 6) | coff));
        uint32 u2 = *(const uint32*)(hbase + ((((uint32)s2) << 6) | coff));
        uint32 u3 = *(const uint32*)(hbase + ((((uint32)s3) << 6) | coff));
        a_[0] = pkmax(a_[0], u0); a_[1] = pkmax(a_[1], u1);
        a_[2] = pkmax(a_[2], u2); a_[3] = pkmax(a_[3], u3);
    }
    for (; k < mm; k += 4) {
        int s = __shfl(sidx, lb + (k >> 2));
        uint32 u = *(const uint32*)(hbase + ((((uint32)s) << 6) | coff));
        a_[0] = pkmax(a_[0], u);
    }
}

__global__ void gather32_kernel(const uint32* __restrict__ hb,
                                const int* __restrict__ offsets,
                                const int* __restrict__ csr_src,
                                uint32* __restrict__ aggB) {
    const int tid  = threadIdx.x;
    const int g    = tid >> 6;
    const int lane = tid & 63;
    const int e    = lane >> 4;        // quarter-wave: edge slot mod 4
    const int c    = lane & 15;        // uint chunk
    const int n0   = (blockIdx.x * NPB + g) * G_NPW;
    if (n0 >= NN) return;

    const char* hbase = (const char*)hb;
    const uint32 coff = (uint32)(c << 2);
    const int lb = e << 4;             // this quarter's lane base
    const int myidx = 4 * c + e;       // R21 permuted window layout

    int beg[G_NPW], end[G_NPW], mm[G_NPW], sidx[G_NPW];
#pragma unroll
    for (int q = 0; q < G_NPW; ++q) {
        const int n = n0 + q;
        const bool ok = (n < NN);
        beg[q] = ok ? offsets[n] : 0;
        end[q] = ok ? offsets[n + 1] : 0;
        int d = end[q] - beg[q];
        mm[q] = d < 64 ? d : 64;
    }
#pragma unroll
    for (int q = 0; q < G_NPW; ++q)
        sidx[q] = (myidx < mm[q]) ? csr_src[beg[q] + myidx] : 0;

    uint32 A[G_NPW][4];
#pragma unroll
    for (int q = 0; q < G_NPW; ++q)
#pragma unroll
        for (int k = 0; k < 4; ++k) A[q][k] = 0;

#pragma unroll
    for (int q = 0; q < G_NPW; ++q)
        g32_window(A[q], sidx[q], mm[q], hbase, coff, e, lb);
    // Rare extra windows (degree > 64)
#pragma unroll
    for (int q = 0; q < G_NPW; ++q) {
        for (int ib = beg[q] + 64; ib < end[q]; ib += 64) {
            const int rem = end[q] - ib;
            const int m = rem < 64 ? rem : 64;
            int sx = (myidx < m) ? csr_src[ib + myidx] : 0;
            g32_window(A[q], sx, m, hbase, coff, e, lb);
        }
    }

#pragma unroll
    for (int q = 0; q < G_NPW; ++q) {
        const int n = n0 + q;
        uint32 r = pkmax(pkmax(A[q][0], A[q][1]), pkmax(A[q][2], A[q][3]));
        r = pkmax(r, (uint32)__shfl_xor((int)r, 16));   // combine edge slots
        r = pkmax(r, (uint32)__shfl_xor((int)r, 32));
        if (lane < 16 && n < NN)
            aggB[(size_t)n * 16 + lane] = (beg[q] == end[q]) ? 0x80008000u : r;
    }
}

// ---------------------------------------------------------------------------
// Dense kernel (R11-proven): one lane per node; 32 fp32 accumulators; wave-
// uniform weight addresses scalarize to s_load. Inputs key-encoded (dec_pk
// on load); MODE 0 stores relu output as keys (relu >= 0 -> OR 0x80008000);
// MODE 2 = log_softmax -> fp32.
template <int DIN, int ASTR, int HSTR, int OSTR, int MODE>
__global__ void dense_kernel(const uint32* __restrict__ aggB,
                             const uint32* __restrict__ hB,
                             const float* __restrict__ Wl,
                             const float* __restrict__ bl,
                             const float* __restrict__ Wr,
                             void* __restrict__ out_v) {
    const int n = blockIdx.x * blockDim.x + threadIdx.x;
    if (n >= NN) return;

    float acc[CD];
#pragma unroll
    for (int j = 0; j < CD; ++j) acc[j] = bl[j];

    {
        const uint32* row = aggB + (size_t)n * ASTR;
        for (int c = 0; c < DIN / 4; ++c) {
            uint2 u = *(const uint2*)&row[c * 2];
            u.x = dec_pk(u.x); u.y = dec_pk(u.y);
            float d0 = b2f_lo(u.x), d1 = b2f_hi(u.x);
            float d2 = b2f_lo(u.y), d3 = b2f_hi(u.y);
            const float* w = Wl + c * 4 * CD;
#pragma unroll
            for (int j = 0; j < CD; ++j)
                acc[j] += d0 * w[j] + d1 * w[CD + j] + d2 * w[2 * CD + j] + d3 * w[3 * CD + j];
        }
        if (DIN % 4) {
            uint32 u = dec_pk(row[(DIN / 4) * 2]);
            float d0 = b2f_lo(u), d1 = b2f_hi(u);
            const float* w = Wl + (DIN - 2) * CD;
#pragma unroll
            for (int j = 0; j < CD; ++j)
                acc[j] += d0 * w[j] + d1 * w[CD + j];
        }
    }
    {
        const uint32* row = hB + (size_t)n * HSTR;
        for (int c = 0; c < DIN / 4; ++c) {
            uint2 u = *(const uint2*)&row[c * 2];
            u.x = dec_pk(u.x); u.y = dec_pk(u.y);
            float d0 = b2f_lo(u.x), d1 = b2f_hi(u.x);
            float d2 = b2f_lo(u.y), d3 = b2f_hi(u.y);
            const float* w = Wr + c * 4 * CD;
#pragma unroll
            for (int j = 0; j < CD; ++j)
                acc[j] += d0 * w[j] + d1 * w[CD + j] + d2 * w[2 * CD + j] + d3 * w[3 * CD + j];
        }
        if (DIN % 4) {
            uint32 u = dec_pk(row[(DIN / 4) * 2]);
            float d0 = b2f_lo(u), d1 = b2f_hi(u);
            const float* w = Wr + (DIN - 2) * CD;
#pragma unroll
            for (int j = 0; j < CD; ++j)
                acc[j] += d0 * w[j] + d1 * w[CD + j];
        }
    }

    if (MODE == 0) {
        uint32* orow = (uint32*)out_v + (size_t)n * OSTR;
#pragma unroll
        for (int c = 0; c < CD / 2; ++c) {
            float a0 = fmaxf(acc[2 * c],     0.0f);
            float a1 = fmaxf(acc[2 * c + 1], 0.0f);
            // relu output >= 0 -> key encode is just setting the top bit
            orow[c] = ((uint32)f2b(a0) | ((uint32)f2b(a1) << 16)) | 0x80008000u;
        }
    } else {
        float m = acc[0];
#pragma unroll
        for (int j = 1; j < CD; ++j) m = fmaxf(m, acc[j]);
        float s = 0.0f;
#pragma unroll
        for (int j = 0; j < CD; ++j) s += expf(acc[j] - m);
        const float lse = m + logf(s);
        float* orow = (float*)out_v + (size_t)n * CD;
#pragma unroll
        for (int j = 0; j < CD; ++j) orow[j] = acc[j] - lse;
    }
}

// ---------------------------------------------------------------------------
extern "C" void kernel_launch(void* const* d_in, const int* in_sizes, int n_in,
                              void* d_out, int out_size, void* d_ws, size_t ws_size,
                              hipStream_t stream) {
    const float* x    = (const float*)d_in[0];
    const void*  edge = d_in[1];
    const float* Wl1 = (const float*)d_in[2];
    const float* bl1 = (const float*)d_in[3];
    const float* Wr1 = (const float*)d_in[4];
    const float* Wl2 = (const float*)d_in[5];
    const float* bl2 = (const float*)d_in[6];
    const float* Wr2 = (const float*)d_in[7];
    const float* Wl3 = (const float*)d_in[8];
    const float* bl3 = (const float*)d_in[9];
    const float* Wr3 = (const float*)d_in[10];

    const int E = in_sizes[1] / 2;

    // Workspace carve-up (256B aligned), ~26 MB. bucketed + hist live in
    // d_out (dead before agg1 is written there); h2b reuses xb (dead after
    // dense-L1); agg3 reuses h1b (dead after dense-L2).
    char* ws = (char*)d_ws;
    size_t off = 0;
    auto carve = [&](size_t bytes) {
        void* p = ws + off;
        off = (off + bytes + 255) & ~(size_t)255;
        return p;
    };
    int*    offsets   = (int*)   carve((size_t)(NN + 1) * 4);
    int*    binTotal  = (int*)   carve((size_t)B1N * 4);
    int*    csr_src   = (int*)   carve((size_t)E * 4);
    uint32* xb        = (uint32*)carve((size_t)NN * 32 * 4);  // 12.8 MB
    uint32* h1b       = (uint32*)carve((size_t)NN * 16 * 4);  // 6.4 MB
    (void)ws_size; (void)n_in; (void)out_size;

    uint32* bucketed = (uint32*)d_out;     // 6.4 MB, dead before agg1
    int*    hist     = (int*)((char*)d_out + (((size_t)E * 4 + 255) & ~(size_t)255));
    uint32* agg1 = (uint32*)d_out;         // L1 agg, stride 32 (12.8 MB = d_out)
    uint32* agg2 = (uint32*)d_out;         // L2 agg, stride 16
    uint32* h2b  = xb;                     // xb dead after dense-L1
    uint32* agg3 = h1b;                    // h1b dead after dense-L2

    // CSR build, LDS-atomic bucketing; cvt fused into the hist dispatch.
    const int nblkA = (E + EPB_A - 1) / EPB_A;     // 782 for E=1.6M
    const int cvtb  = (NN * 32 + 255) / 256;       // 12500
    cvt_hist_kernel<<<nblkA + cvtb, 256, 0, stream>>>(x, xb, edge, E, hist, nblkA);
    scanA_kernel<<<B1N, 256, 0, stream>>>(hist, nblkA, binTotal);
    scatter_kernel<<<nblkA, 256, 0, stream>>>(edge, E, hist, binTotal, bucketed);
    bucket_kernel<<<B1N, 256, 0, stream>>>(bucketed, binTotal, offsets, csr_src);

    const int gb = (NN + NPB * G_NPW - 1) / (NPB * G_NPW);   // 4 nodes per wave
    const int db = (NN + 255) / 256;                         // lane per node

    // Layer 1: 50 -> 32, relu
    gather50_kernel<<<gb, 256, 0, stream>>>(xb, offsets, csr_src, agg1);
    dense_kernel<50, 32, 32, 16, 0><<<db, 256, 0, stream>>>(agg1, xb, Wl1, bl1, Wr1, h1b);
    // Layer 2: 32 -> 32, relu
    gather32_kernel<<<gb, 256, 0, stream>>>(h1b, offsets, csr_src, agg2);
    dense_kernel<32, 16, 16, 16, 0><<<db, 256, 0, stream>>>(agg2, h1b, Wl2, bl2, Wr2, h2b);
    // Layer 3: 32 -> 32, log_softmax -> fp32 d_out
    gather32_kernel<<<gb, 256, 0, stream>>>(h2b, offsets, csr_src, agg3);
    dense_kernel<32, 16, 16, 0, 2><<<db, 256, 0, stream>>>(agg3, h2b, Wl3, bl3, Wr3, d_out);
}